// Round 11
// baseline (4254.509 us; speedup 1.0000x reference)
//
#include <hip/hip_runtime.h>
#include <hip/hip_bf16.h>

#define BB 16
#define DEPTH 24
#define DM 192
#define DI 384
#define DS 16
#define DC 4
#define DTR 12
#define LL 320
#define NX 256
#define NZ 64
#define NT (BB * LL)
#define NC 10         // scan chunks
#define LC 32         // chunk length
#define EPSV 1e-5f

__device__ inline float siluf(float x) { return x / (1.f + __expf(-x)); }
__device__ inline float softplusf(float x) {
    return (x > 20.f) ? x : log1pf(expf(x));
}
__device__ inline float wave_sum64(float v) {
    #pragma unroll
    for (int o = 32; o > 0; o >>= 1) v += __shfl_xor(v, o);
    return v;
}

// ---------- add + LN prenorm (used ONCE, on patch output) ----------
__global__ __launch_bounds__(256) void addnorm_kernel(const float* hidden,
                                                      float* __restrict__ residual,
                                                      float* hn,
                                                      const float* __restrict__ w,
                                                      const float* __restrict__ bias,
                                                      size_t off) {
    int t = blockIdx.x * 4 + (threadIdx.x >> 6);
    int lane = threadIdx.x & 63;
    size_t base = (size_t)t * DM;
    float a = hidden[base + lane];
    float b = hidden[base + 64 + lane];
    float c = hidden[base + 128 + lane];
    residual[base + lane] = a;
    residual[base + 64 + lane] = b;
    residual[base + 128 + lane] = c;
    float mu = wave_sum64(a + b + c) * (1.f / 192.f);
    float va = a - mu, vb = b - mu, vc = c - mu;
    float var = wave_sum64(va * va + vb * vb + vc * vc) * (1.f / 192.f);
    float inv = rsqrtf(var + EPSV);
    hn[base + lane]       = va * inv * w[off + lane]       + bias[off + lane];
    hn[base + 64 + lane]  = vb * inv * w[off + 64 + lane]  + bias[off + 64 + lane];
    hn[base + 128 + lane] = vc * inv * w[off + 128 + lane] + bias[off + 128 + lane];
}

// ---------- register-tiled GEMM (in_proj), b128 weight reads ----------
// Block: 256 thr = 4 waves; wave owns 8 tokens (broadcast x reads, ~3 cyc);
// lane owns NO cols (stride 64, lane-distributed b128, ~12 cyc). Row stride
// KT+4 (==28 mod 32 for KT=24): 8-row bank-starts distinct -> conflict-free.
// KT=24,NO=4 -> 31.5 KB LDS, 5 blk/CU.
template<int K, int KT, int NO>
__global__ __launch_bounds__(256) void gemm_rt(const float* __restrict__ x,
                                               const float* __restrict__ w,
                                               size_t woff,
                                               float* __restrict__ out, int N) {
    constexpr int NCOL = 64 * NO;
    constexpr int KC = KT / 4;
    __shared__ float xs[32][KT + 4];
    __shared__ float ws[NCOL][KT + 4];
    int t0 = blockIdx.x * 32;
    int j0 = blockIdx.y * NCOL;
    int lane = threadIdx.x & 63;
    int wv = threadIdx.x >> 6;
    float acc[8][NO];
    #pragma unroll
    for (int t = 0; t < 8; t++)
        #pragma unroll
        for (int o = 0; o < NO; o++) acc[t][o] = 0.f;

    for (int kt = 0; kt < K; kt += KT) {
        for (int idx = threadIdx.x; idx < 32 * KC; idx += 256) {
            int tt = idx / KC, kc = idx % KC;
            float4 v = *(const float4*)&x[(size_t)(t0 + tt) * K + kt + kc * 4];
            *(float4*)&xs[tt][kc * 4] = v;
        }
        for (int idx = threadIdx.x; idx < NCOL * KC; idx += 256) {
            int jj = idx / KC, kc = idx % KC;
            float4 v = *(const float4*)&w[woff + (size_t)(j0 + jj) * K + kt + kc * 4];
            *(float4*)&ws[jj][kc * 4] = v;
        }
        __syncthreads();
        #pragma unroll 2
        for (int kk = 0; kk < KT; kk += 4) {
            float4 xv[8];
            #pragma unroll
            for (int t = 0; t < 8; t++)
                xv[t] = *(const float4*)&xs[wv * 8 + t][kk];
            #pragma unroll
            for (int o = 0; o < NO; o++) {
                float4 wv4 = *(const float4*)&ws[lane + 64 * o][kk];
                #pragma unroll
                for (int t = 0; t < 8; t++)
                    acc[t][o] += xv[t].x * wv4.x + xv[t].y * wv4.y
                               + xv[t].z * wv4.z + xv[t].w * wv4.w;
            }
        }
        __syncthreads();
    }
    #pragma unroll
    for (int t = 0; t < 8; t++)
        #pragma unroll
        for (int o = 0; o < NO; o++)
            out[(size_t)(t0 + wv * 8 + t) * N + j0 + lane + 64 * o] = acc[t][o];
}

// ---------- out_proj GEMM + residual-add + LN epilogue ----------
// Block: 16 tokens x ALL 192 cols; grid NT/16 = 320; 4 waves x 4 tokens;
// lane owns cols {lane, lane+64, lane+128}. After GEMM, each wave holds the
// addnorm layout per token -> fuse residual+=h, hn = LN(res)*lnw+lnb.
// last=1: write LN to out (fnorm), skip residual store.
// LDS: xs[16][52] + ws[192][52] = 43.3 KB -> 3 blocks/CU.
__global__ __launch_bounds__(256) void gemm_out_ln(const float* __restrict__ y,
                                                   const float* __restrict__ w,
                                                   size_t woff,
                                                   float* __restrict__ residual,
                                                   float* __restrict__ hn,
                                                   const float* __restrict__ lnw,
                                                   const float* __restrict__ lnb,
                                                   size_t lnoff, int last) {
    __shared__ float xs[16][52];
    __shared__ float ws[192][52];
    int t0 = blockIdx.x * 16;
    int lane = threadIdx.x & 63;
    int wv = threadIdx.x >> 6;
    float acc[4][3];
    #pragma unroll
    for (int t = 0; t < 4; t++)
        #pragma unroll
        for (int o = 0; o < 3; o++) acc[t][o] = 0.f;

    for (int kt = 0; kt < 384; kt += 48) {
        for (int idx = threadIdx.x; idx < 16 * 12; idx += 256) {
            int tt = idx / 12, kc = idx % 12;
            *(float4*)&xs[tt][kc * 4] =
                *(const float4*)&y[(size_t)(t0 + tt) * 384 + kt + kc * 4];
        }
        for (int idx = threadIdx.x; idx < 192 * 12; idx += 256) {
            int jj = idx / 12, kc = idx % 12;
            *(float4*)&ws[jj][kc * 4] =
                *(const float4*)&w[woff + (size_t)jj * 384 + kt + kc * 4];
        }
        __syncthreads();
        #pragma unroll 2
        for (int kk = 0; kk < 48; kk += 4) {
            float4 xv[4];
            #pragma unroll
            for (int t = 0; t < 4; t++)
                xv[t] = *(const float4*)&xs[wv * 4 + t][kk];
            #pragma unroll
            for (int o = 0; o < 3; o++) {
                float4 wv4 = *(const float4*)&ws[lane + 64 * o][kk];
                #pragma unroll
                for (int t = 0; t < 4; t++)
                    acc[t][o] += xv[t].x * wv4.x + xv[t].y * wv4.y
                               + xv[t].z * wv4.z + xv[t].w * wv4.w;
            }
        }
        __syncthreads();
    }
    // epilogue: residual += h; LN; write hn (or final out)
    #pragma unroll
    for (int t = 0; t < 4; t++) {
        size_t base = (size_t)(t0 + wv * 4 + t) * DM;
        float a = acc[t][0] + residual[base + lane];
        float b = acc[t][1] + residual[base + 64 + lane];
        float c = acc[t][2] + residual[base + 128 + lane];
        if (!last) {
            residual[base + lane]       = a;
            residual[base + 64 + lane]  = b;
            residual[base + 128 + lane] = c;
        }
        float mu = wave_sum64(a + b + c) * (1.f / 192.f);
        float va = a - mu, vb = b - mu, vc = c - mu;
        float var = wave_sum64(va * va + vb * vb + vc * vc) * (1.f / 192.f);
        float inv = rsqrtf(var + EPSV);
        hn[base + lane]       = va * inv * lnw[lnoff + lane]       + lnb[lnoff + lane];
        hn[base + 64 + lane]  = vb * inv * lnw[lnoff + 64 + lane]  + lnb[lnoff + 64 + lane];
        hn[base + 128 + lane] = vc * inv * lnw[lnoff + 128 + lane] + lnb[lnoff + 128 + lane];
    }
}

// ---------- patch embed (both images, one launch). KT=96, b128 reads, 256 thr ----------
__global__ __launch_bounds__(256) void patch_rt(const float* __restrict__ x_img,
                                                const float* __restrict__ z_img,
                                                const float* __restrict__ w,
                                                const float* __restrict__ bias,
                                                const float* __restrict__ pos_x,
                                                const float* __restrict__ pos_z,
                                                float* __restrict__ hidden) {
    __shared__ float xs[32][100];
    __shared__ float ws[64][100];
    bool isx = blockIdx.x < (BB * NX / 32);
    const float* img = isx ? x_img : z_img;
    const float* pos = isx ? pos_x : pos_z;
    int side = isx ? 16 : 8;
    int tok_off = isx ? NZ : 0;
    int ntok = side * side;
    int pt0 = (isx ? blockIdx.x : blockIdx.x - BB * NX / 32) * 32;
    int j0 = blockIdx.y * 64;
    int S = side * 16;
    int lane = threadIdx.x & 63;
    int wv = threadIdx.x >> 6;
    float acc[8];
    #pragma unroll
    for (int t = 0; t < 8; t++) acc[t] = 0.f;

    for (int kt = 0; kt < 768; kt += 96) {
        for (int idx = threadIdx.x; idx < 32 * 24; idx += 256) {
            int tt = idx / 24, kc = idx % 24;
            int k = kt + kc * 4;
            int c = k >> 8, p = k & 255, pi = p >> 4, pj = p & 15;
            int patch = pt0 + tt;
            int b = patch / ntok, t = patch % ntok;
            int ph = t / side, pw = t % side;
            float4 v = *(const float4*)&img[((size_t)(b * 3 + c) * S + ph * 16 + pi) * S
                                            + pw * 16 + pj];
            *(float4*)&xs[tt][kc * 4] = v;
        }
        for (int idx = threadIdx.x; idx < 64 * 24; idx += 256) {
            int jj = idx / 24, kc = idx % 24;
            float4 v = *(const float4*)&w[(size_t)(j0 + jj) * 768 + kt + kc * 4];
            *(float4*)&ws[jj][kc * 4] = v;
        }
        __syncthreads();
        #pragma unroll 2
        for (int kk = 0; kk < 96; kk += 4) {
            float4 xv[8];
            #pragma unroll
            for (int t = 0; t < 8; t++)
                xv[t] = *(const float4*)&xs[wv * 8 + t][kk];
            float4 wv4 = *(const float4*)&ws[lane][kk];
            #pragma unroll
            for (int t = 0; t < 8; t++)
                acc[t] += xv[t].x * wv4.x + xv[t].y * wv4.y
                        + xv[t].z * wv4.z + xv[t].w * wv4.w;
        }
        __syncthreads();
    }
    float bj = bias[j0 + lane];
    #pragma unroll
    for (int t = 0; t < 8; t++) {
        int patch = pt0 + wv * 8 + t;
        int b = patch / ntok, tk = patch % ntok;
        hidden[((size_t)b * LL + tok_off + tk) * DM + j0 + lane] =
            acc[t] + bj + pos[(size_t)tk * DM + j0 + lane];
    }
}

// ---------- fused conv+silu -> x_proj (reg-tiled) -> dt_proj. block = 16 tokens ----------
__global__ __launch_bounds__(256) void xpd_kernel(const float* __restrict__ xz,
                                                  const float* __restrict__ cw,
                                                  const float* __restrict__ cb,
                                                  const float* __restrict__ xpw,
                                                  const float* __restrict__ dtw,
                                                  const float* __restrict__ dtbias,
                                                  float* __restrict__ xc,
                                                  float* __restrict__ dbl,
                                                  float* __restrict__ dtbuf,
                                                  int layer) {
    __shared__ float smem[5760];
    float* xs   = smem;          // [16][52]
    float* ws   = smem + 832;    // [64][52]
    float* sdbl = smem;          // [16][48]
    float* sdtw = smem + 768;    // [384][13] -> bank (13d+r)%32, 2-way free

    int t0 = blockIdx.x * 16;
    int l0 = t0 % LL;
    int lane = threadIdx.x & 63;
    int wv = threadIdx.x >> 6;
    const float* cwl = cw  + (size_t)layer * DI * DC;
    const float* cbl = cb  + (size_t)layer * DI;
    const float* xpl = xpw + (size_t)layer * 44 * DI;
    float acc[4] = {0.f, 0.f, 0.f, 0.f};

    for (int kt = 0; kt < DI; kt += 48) {
        for (int idx = threadIdx.x; idx < 16 * 12; idx += 256) {
            int tt = idx / 12, kc = idx % 12;
            int d = kt + kc * 4;
            float4 a = *(const float4*)&cbl[d];
            float4 cw0 = *(const float4*)&cwl[(size_t)(d + 0) * 4];
            float4 cw1 = *(const float4*)&cwl[(size_t)(d + 1) * 4];
            float4 cw2 = *(const float4*)&cwl[(size_t)(d + 2) * 4];
            float4 cw3 = *(const float4*)&cwl[(size_t)(d + 3) * 4];
            const float* c0 = &cw0.x;
            const float* c1 = &cw1.x;
            const float* c2 = &cw2.x;
            const float* c3 = &cw3.x;
            #pragma unroll
            for (int rr = 0; rr < 4; rr++) {
                int l = l0 + tt - 3 + rr;
                float4 v = make_float4(0.f, 0.f, 0.f, 0.f);
                if (l >= 0)
                    v = *(const float4*)&xz[(size_t)(t0 + tt - 3 + rr) * 768 + d];
                a.x += c0[rr] * v.x;
                a.y += c1[rr] * v.y;
                a.z += c2[rr] * v.z;
                a.w += c3[rr] * v.w;
            }
            a.x = siluf(a.x); a.y = siluf(a.y); a.z = siluf(a.z); a.w = siluf(a.w);
            *(float4*)&xs[tt * 52 + kc * 4] = a;
            *(float4*)&xc[(size_t)(t0 + tt) * DI + d] = a;
        }
        for (int idx = threadIdx.x; idx < 64 * 12; idx += 256) {
            int jj = idx / 12, kc = idx % 12;
            float4 v = make_float4(0.f, 0.f, 0.f, 0.f);
            if (jj < 44)
                v = *(const float4*)&xpl[(size_t)jj * DI + kt + kc * 4];
            *(float4*)&ws[jj * 52 + kc * 4] = v;
        }
        __syncthreads();
        const float* wr0 = ws + lane * 52;
        #pragma unroll 4
        for (int kk = 0; kk < 48; kk += 4) {
            float4 xv0 = *(const float4*)&xs[(wv * 4 + 0) * 52 + kk];
            float4 xv1 = *(const float4*)&xs[(wv * 4 + 1) * 52 + kk];
            float4 xv2 = *(const float4*)&xs[(wv * 4 + 2) * 52 + kk];
            float4 xv3 = *(const float4*)&xs[(wv * 4 + 3) * 52 + kk];
            float4 wv4 = *(const float4*)&wr0[kk];
            acc[0] += xv0.x * wv4.x + xv0.y * wv4.y + xv0.z * wv4.z + xv0.w * wv4.w;
            acc[1] += xv1.x * wv4.x + xv1.y * wv4.y + xv1.z * wv4.z + xv1.w * wv4.w;
            acc[2] += xv2.x * wv4.x + xv2.y * wv4.y + xv2.z * wv4.z + xv2.w * wv4.w;
            acc[3] += xv3.x * wv4.x + xv3.y * wv4.y + xv3.z * wv4.z + xv3.w * wv4.w;
        }
        __syncthreads();
    }
    if (lane < 44) {
        #pragma unroll
        for (int t = 0; t < 4; t++) {
            sdbl[(wv * 4 + t) * 48 + lane] = acc[t];
            dbl[(size_t)(t0 + wv * 4 + t) * 44 + lane] = acc[t];
        }
    }
    const float* dwl = dtw + (size_t)layer * DI * DTR;
    for (int idx = threadIdx.x; idx < DI * DTR; idx += 256) {
        int d = idx / 12, rr = idx % 12;
        sdtw[d * 13 + rr] = dwl[idx];
    }
    __syncthreads();
    const float* dbb = dtbias + (size_t)layer * DI;
    for (int idx = threadIdx.x; idx < 16 * DI; idx += 256) {
        int tt = idx / DI, d = idx % DI;
        float a = dbb[d];
        const float* br = sdbl + tt * 48;
        const float* wr = sdtw + d * 13;
        #pragma unroll
        for (int rr = 0; rr < 12; rr++) a += br[rr] * wr[rr];
        dtbuf[(size_t)(t0 + tt) * DI + d] = softplusf(a);
    }
}

// ---------- fused chunked scan: phase A + LDS prefix + replay ----------
__global__ __launch_bounds__(320) void scan_fused(const float* __restrict__ dt,
                                                  const float* xc,
                                                  const float* __restrict__ dbl,
                                                  const float* __restrict__ xz,
                                                  const float* __restrict__ A_log,
                                                  const float* __restrict__ Dskip,
                                                  float* y,
                                                  size_t aoff, size_t doff) {
    __shared__ float sP[NC * 8 * 16];
    __shared__ float sH[NC * 8 * 16];
    int b = blockIdx.x / (DI / 8);
    int dbase = (blockIdx.x % (DI / 8)) * 8;
    int quad = threadIdx.x >> 2;
    int n0 = threadIdx.x & 3;
    int c = quad >> 3;
    int dl = quad & 7;
    int d = dbase + dl;
    float4 Al = *(const float4*)&A_log[aoff + (size_t)d * DS + n0 * 4];
    float A0 = -expf(Al.x), A1 = -expf(Al.y), A2 = -expf(Al.z), A3 = -expf(Al.w);
    int tbase = b * LL + c * LC;

    float h0 = 0.f, h1 = 0.f, h2 = 0.f, h3 = 0.f;
    float P0 = 1.f, P1 = 1.f, P2 = 1.f, P3 = 1.f;
    for (int l = 0; l < LC; l++) {
        size_t t = (size_t)tbase + l;
        float dtv = dt[t * DI + d];
        float xcv = xc[t * DI + d];
        float4 B4 = *(const float4*)&dbl[t * 44 + DTR + n0 * 4];
        float s = dtv * xcv;
        float e0 = __expf(dtv * A0), e1 = __expf(dtv * A1);
        float e2 = __expf(dtv * A2), e3 = __expf(dtv * A3);
        h0 = e0 * h0 + s * B4.x;  P0 *= e0;
        h1 = e1 * h1 + s * B4.y;  P1 *= e1;
        h2 = e2 * h2 + s * B4.z;  P2 *= e2;
        h3 = e3 * h3 + s * B4.w;  P3 *= e3;
    }
    int si = quad * 16 + n0 * 4;
    *(float4*)&sP[si] = make_float4(P0, P1, P2, P3);
    *(float4*)&sH[si] = make_float4(h0, h1, h2, h3);
    __syncthreads();

    h0 = h1 = h2 = h3 = 0.f;
    for (int cc = 0; cc < c; cc++) {
        int gi = (cc * 8 + dl) * 16 + n0 * 4;
        float4 P4 = *(const float4*)&sP[gi];
        float4 H4 = *(const float4*)&sH[gi];
        h0 = P4.x * h0 + H4.x;
        h1 = P4.y * h1 + H4.y;
        h2 = P4.z * h2 + H4.z;
        h3 = P4.w * h3 + H4.w;
    }

    float Dv = Dskip[doff + d];
    for (int l = 0; l < LC; l++) {
        size_t t = (size_t)tbase + l;
        float dtv = dt[t * DI + d];
        float xcv = xc[t * DI + d];
        float4 B4 = *(const float4*)&dbl[t * 44 + DTR + n0 * 4];
        float4 C4 = *(const float4*)&dbl[t * 44 + DTR + DS + n0 * 4];
        float s = dtv * xcv;
        float e0 = __expf(dtv * A0), e1 = __expf(dtv * A1);
        float e2 = __expf(dtv * A2), e3 = __expf(dtv * A3);
        h0 = e0 * h0 + s * B4.x;
        h1 = e1 * h1 + s * B4.y;
        h2 = e2 * h2 + s * B4.z;
        h3 = e3 * h3 + s * B4.w;
        float p = h0 * C4.x + h1 * C4.y + h2 * C4.z + h3 * C4.w;
        p += __shfl_xor(p, 1);
        p += __shfl_xor(p, 2);
        if (n0 == 0) {
            float zg = xz[t * (2 * DI) + DI + d];
            y[t * DI + d] = (p + xcv * Dv) * siluf(zg);
        }
    }
}

extern "C" void kernel_launch(void* const* d_in, const int* in_sizes, int n_in,
                              void* d_out, int out_size, void* d_ws, size_t ws_size,
                              hipStream_t stream) {
    const float* x_img   = (const float*)d_in[0];
    const float* z_img   = (const float*)d_in[1];
    const float* patch_w = (const float*)d_in[2];
    const float* patch_b = (const float*)d_in[3];
    const float* pos_x   = (const float*)d_in[4];
    const float* pos_z   = (const float*)d_in[5];
    const float* ln_w    = (const float*)d_in[6];
    const float* ln_b    = (const float*)d_in[7];
    const float* in_w    = (const float*)d_in[8];
    const float* conv_w  = (const float*)d_in[9];
    const float* conv_b  = (const float*)d_in[10];
    const float* xproj_w = (const float*)d_in[11];
    const float* dt_w    = (const float*)d_in[12];
    const float* dt_b    = (const float*)d_in[13];
    const float* A_log   = (const float*)d_in[14];
    const float* D_skip  = (const float*)d_in[15];
    const float* out_w   = (const float*)d_in[16];
    const float* fnorm_w = (const float*)d_in[17];
    const float* fnorm_b = (const float*)d_in[18];

    // ws layout (floats), ~45 MB total (<52 MB proven):
    float* hidden   = (float*)d_ws;                         // NT*DM (patch out + hn)
    float* residual = hidden   + (size_t)NT * DM;           // NT*DM
    float* xz       = residual + (size_t)NT * DM;           // NT*768
    float* xc       = xz       + (size_t)NT * 2 * DI;       // NT*DI
    float* dbl      = xc       + (size_t)NT * DI;           // NT*44
    float* dtbuf    = dbl      + (size_t)NT * 44;           // NT*DI
    float* hn       = hidden;   // alias (LN output lives where hidden was)
    float* yb       = xc;       // alias (read-before-write per step)

    // z-first concat: z tokens 0..63, x tokens 64..319 (one combined launch)
    {
        dim3 gp((BB * NX + BB * NZ) / 32, 3);   // (160, 3)
        patch_rt<<<gp, 256, 0, stream>>>(x_img, z_img, patch_w, patch_b,
                                         pos_x, pos_z, hidden);
    }

    // layer-0 prenorm on patch output (residual := patch tokens)
    addnorm_kernel<<<NT / 4, 256, 0, stream>>>(
        hidden, residual, hn, ln_w, ln_b, 0);

    const int scan_blocks = BB * (DI / 8);   // 768 blocks of 320 thr
    for (int i = 0; i < DEPTH; i++) {
        {
            dim3 g(NT / 32, 3);   // 480 blocks, NCOL=256, KT=24 -> 31.5 KB LDS
            gemm_rt<192, 24, 4><<<g, 256, 0, stream>>>(
                hn, in_w, (size_t)i * 768 * 192, xz, 768);
        }
        xpd_kernel<<<NT / 16, 256, 0, stream>>>(
            xz, conv_w, conv_b, xproj_w, dt_w, dt_b, xc, dbl, dtbuf, i);
        scan_fused<<<scan_blocks, 320, 0, stream>>>(
            dtbuf, xc, dbl, xz, A_log, D_skip, yb,
            (size_t)i * DI * DS, (size_t)i * DI);
        // out_proj + residual-add + prenorm of layer i+1 (or final norm)
        if (i < DEPTH - 1) {
            gemm_out_ln<<<NT / 16, 256, 0, stream>>>(
                yb, out_w, (size_t)i * 192 * 384, residual, hn,
                ln_w, ln_b, (size_t)(i + 1) * DM, 0);
        } else {
            gemm_out_ln<<<NT / 16, 256, 0, stream>>>(
                yb, out_w, (size_t)i * 192 * 384, residual, (float*)d_out,
                fnorm_w, fnorm_b, 0, 1);
        }
    }
}

// Round 12
// 3685.177 us; speedup vs baseline: 1.1545x; 1.1545x over previous
//
#include <hip/hip_runtime.h>
#include <hip/hip_bf16.h>

#define BB 16
#define DEPTH 24
#define DM 192
#define DI 384
#define DS 16
#define DC 4
#define DTR 12
#define LL 320
#define NX 256
#define NZ 64
#define NT (BB * LL)
#define NC 10         // scan chunks
#define LC 32         // chunk length
#define EPSV 1e-5f

__device__ inline float siluf(float x) { return x / (1.f + __expf(-x)); }
__device__ inline float softplusf(float x) {
    return (x > 20.f) ? x : log1pf(expf(x));
}
__device__ inline float wave_sum64(float v) {
    #pragma unroll
    for (int o = 32; o > 0; o >>= 1) v += __shfl_xor(v, o);
    return v;
}

// ---------- add + LN prenorm: one wave per token, 4 tokens/block ----------
__global__ __launch_bounds__(256) void addnorm_kernel(const float* hidden,
                                                      float* __restrict__ residual,
                                                      float* hn,
                                                      const float* __restrict__ w,
                                                      const float* __restrict__ bias,
                                                      size_t off, int first) {
    int t = blockIdx.x * 4 + (threadIdx.x >> 6);
    int lane = threadIdx.x & 63;
    size_t base = (size_t)t * DM;
    float a = hidden[base + lane];
    float b = hidden[base + 64 + lane];
    float c = hidden[base + 128 + lane];
    if (!first) {
        a += residual[base + lane];
        b += residual[base + 64 + lane];
        c += residual[base + 128 + lane];
    }
    residual[base + lane] = a;
    residual[base + 64 + lane] = b;
    residual[base + 128 + lane] = c;
    float mu = wave_sum64(a + b + c) * (1.f / 192.f);
    float va = a - mu, vb = b - mu, vc = c - mu;
    float var = wave_sum64(va * va + vb * vb + vc * vc) * (1.f / 192.f);
    float inv = rsqrtf(var + EPSV);
    hn[base + lane]       = va * inv * w[off + lane]       + bias[off + lane];
    hn[base + 64 + lane]  = vb * inv * w[off + 64 + lane]  + bias[off + 64 + lane];
    hn[base + 128 + lane] = vc * inv * w[off + 128 + lane] + bias[off + 128 + lane];
}

// ---------- register-tiled GEMM, b128 weight reads ----------
// Block: 256 thr = 4 waves; wave owns 8 tokens (broadcast x reads, ~3 cyc);
// lane owns NO cols (stride 64, lane-distributed b128, ~12 cyc). Row stride
// KT+4 (==28 mod 32 for KT=24, ==4 mod 32 for KT=48/96): 8-row bank-starts
// all distinct -> conflict-free. in-proj: KT=24,NO=4 -> 31.5 KB, 5 blk/CU.
template<int K, int KT, int NO>
__global__ __launch_bounds__(256) void gemm_rt(const float* __restrict__ x,
                                               const float* __restrict__ w,
                                               size_t woff,
                                               float* __restrict__ out, int N) {
    constexpr int NCOL = 64 * NO;
    constexpr int KC = KT / 4;
    __shared__ float xs[32][KT + 4];
    __shared__ float ws[NCOL][KT + 4];
    int t0 = blockIdx.x * 32;
    int j0 = blockIdx.y * NCOL;
    int lane = threadIdx.x & 63;
    int wv = threadIdx.x >> 6;
    float acc[8][NO];
    #pragma unroll
    for (int t = 0; t < 8; t++)
        #pragma unroll
        for (int o = 0; o < NO; o++) acc[t][o] = 0.f;

    for (int kt = 0; kt < K; kt += KT) {
        for (int idx = threadIdx.x; idx < 32 * KC; idx += 256) {
            int tt = idx / KC, kc = idx % KC;
            float4 v = *(const float4*)&x[(size_t)(t0 + tt) * K + kt + kc * 4];
            *(float4*)&xs[tt][kc * 4] = v;
        }
        for (int idx = threadIdx.x; idx < NCOL * KC; idx += 256) {
            int jj = idx / KC, kc = idx % KC;
            float4 v = *(const float4*)&w[woff + (size_t)(j0 + jj) * K + kt + kc * 4];
            *(float4*)&ws[jj][kc * 4] = v;
        }
        __syncthreads();
        #pragma unroll 2
        for (int kk = 0; kk < KT; kk += 4) {
            float4 xv[8];
            #pragma unroll
            for (int t = 0; t < 8; t++)
                xv[t] = *(const float4*)&xs[wv * 8 + t][kk];
            #pragma unroll
            for (int o = 0; o < NO; o++) {
                float4 wv4 = *(const float4*)&ws[lane + 64 * o][kk];
                #pragma unroll
                for (int t = 0; t < 8; t++)
                    acc[t][o] += xv[t].x * wv4.x + xv[t].y * wv4.y
                               + xv[t].z * wv4.z + xv[t].w * wv4.w;
            }
        }
        __syncthreads();
    }
    #pragma unroll
    for (int t = 0; t < 8; t++)
        #pragma unroll
        for (int o = 0; o < NO; o++)
            out[(size_t)(t0 + wv * 8 + t) * N + j0 + lane + 64 * o] = acc[t][o];
}

// ---------- patch embed (both images, one launch). KT=96, b128 reads, 256 thr ----------
__global__ __launch_bounds__(256) void patch_rt(const float* __restrict__ x_img,
                                                const float* __restrict__ z_img,
                                                const float* __restrict__ w,
                                                const float* __restrict__ bias,
                                                const float* __restrict__ pos_x,
                                                const float* __restrict__ pos_z,
                                                float* __restrict__ hidden) {
    __shared__ float xs[32][100];
    __shared__ float ws[64][100];
    bool isx = blockIdx.x < (BB * NX / 32);
    const float* img = isx ? x_img : z_img;
    const float* pos = isx ? pos_x : pos_z;
    int side = isx ? 16 : 8;
    int tok_off = isx ? NZ : 0;
    int ntok = side * side;
    int pt0 = (isx ? blockIdx.x : blockIdx.x - BB * NX / 32) * 32;
    int j0 = blockIdx.y * 64;
    int S = side * 16;
    int lane = threadIdx.x & 63;
    int wv = threadIdx.x >> 6;
    float acc[8];
    #pragma unroll
    for (int t = 0; t < 8; t++) acc[t] = 0.f;

    for (int kt = 0; kt < 768; kt += 96) {
        for (int idx = threadIdx.x; idx < 32 * 24; idx += 256) {
            int tt = idx / 24, kc = idx % 24;
            int k = kt + kc * 4;
            int c = k >> 8, p = k & 255, pi = p >> 4, pj = p & 15;
            int patch = pt0 + tt;
            int b = patch / ntok, t = patch % ntok;
            int ph = t / side, pw = t % side;
            float4 v = *(const float4*)&img[((size_t)(b * 3 + c) * S + ph * 16 + pi) * S
                                            + pw * 16 + pj];
            *(float4*)&xs[tt][kc * 4] = v;
        }
        for (int idx = threadIdx.x; idx < 64 * 24; idx += 256) {
            int jj = idx / 24, kc = idx % 24;
            float4 v = *(const float4*)&w[(size_t)(j0 + jj) * 768 + kt + kc * 4];
            *(float4*)&ws[jj][kc * 4] = v;
        }
        __syncthreads();
        #pragma unroll 2
        for (int kk = 0; kk < 96; kk += 4) {
            float4 xv[8];
            #pragma unroll
            for (int t = 0; t < 8; t++)
                xv[t] = *(const float4*)&xs[wv * 8 + t][kk];
            float4 wv4 = *(const float4*)&ws[lane][kk];
            #pragma unroll
            for (int t = 0; t < 8; t++)
                acc[t] += xv[t].x * wv4.x + xv[t].y * wv4.y
                        + xv[t].z * wv4.z + xv[t].w * wv4.w;
        }
        __syncthreads();
    }
    float bj = bias[j0 + lane];
    #pragma unroll
    for (int t = 0; t < 8; t++) {
        int patch = pt0 + wv * 8 + t;
        int b = patch / ntok, tk = patch % ntok;
        hidden[((size_t)b * LL + tok_off + tk) * DM + j0 + lane] =
            acc[t] + bj + pos[(size_t)tk * DM + j0 + lane];
    }
}

// ---------- fused conv+silu -> x_proj -> dt_proj. block = 8 tokens, grid 640 ----------
// 8-token split doubles the grid (640 vs 320: 62% -> ~83% CU utilization).
// Phase 1 LDS: xs[8][100] @0, ws[64][100] @800 (28.8 KB, KT=96, 4 stages).
// Phase 2 LDS: sdbl[8][48] @0, sdtw[384][13] @384 (re-uses phase-1 space).
// Wave owns 2 tokens; lane owns col `lane` (cols 44..63 zero-padded).
__global__ __launch_bounds__(256) void xpd_kernel(const float* __restrict__ xz,
                                                  const float* __restrict__ cw,
                                                  const float* __restrict__ cb,
                                                  const float* __restrict__ xpw,
                                                  const float* __restrict__ dtw,
                                                  const float* __restrict__ dtbias,
                                                  float* __restrict__ xc,
                                                  float* __restrict__ dbl,
                                                  float* __restrict__ dtbuf,
                                                  int layer) {
    __shared__ float smem[7200];
    float* xs   = smem;          // [8][100]
    float* ws   = smem + 800;    // [64][100]
    float* sdbl = smem;          // [8][48]
    float* sdtw = smem + 384;    // [384][13] -> bank (13d+r)%32, 2-way free

    int t0 = blockIdx.x * 8;
    int l0 = t0 % LL;
    int lane = threadIdx.x & 63;
    int wv = threadIdx.x >> 6;
    const float* cwl = cw  + (size_t)layer * DI * DC;
    const float* cbl = cb  + (size_t)layer * DI;
    const float* xpl = xpw + (size_t)layer * 44 * DI;
    float acc[2] = {0.f, 0.f};

    for (int kt = 0; kt < DI; kt += 96) {
        // conv+silu staging, 4 channels/item via float4 (8*24 = 192 items)
        for (int idx = threadIdx.x; idx < 8 * 24; idx += 256) {
            int tt = idx / 24, kc = idx % 24;
            int d = kt + kc * 4;
            float4 a = *(const float4*)&cbl[d];
            float4 cw0 = *(const float4*)&cwl[(size_t)(d + 0) * 4];
            float4 cw1 = *(const float4*)&cwl[(size_t)(d + 1) * 4];
            float4 cw2 = *(const float4*)&cwl[(size_t)(d + 2) * 4];
            float4 cw3 = *(const float4*)&cwl[(size_t)(d + 3) * 4];
            const float* c0 = &cw0.x;
            const float* c1 = &cw1.x;
            const float* c2 = &cw2.x;
            const float* c3 = &cw3.x;
            #pragma unroll
            for (int rr = 0; rr < 4; rr++) {
                int l = l0 + tt - 3 + rr;
                float4 v = make_float4(0.f, 0.f, 0.f, 0.f);
                if (l >= 0)
                    v = *(const float4*)&xz[(size_t)(t0 + tt - 3 + rr) * 768 + d];
                a.x += c0[rr] * v.x;
                a.y += c1[rr] * v.y;
                a.z += c2[rr] * v.z;
                a.w += c3[rr] * v.w;
            }
            a.x = siluf(a.x); a.y = siluf(a.y); a.z = siluf(a.z); a.w = siluf(a.w);
            *(float4*)&xs[tt * 100 + kc * 4] = a;
            *(float4*)&xc[(size_t)(t0 + tt) * DI + d] = a;
        }
        // weight tile (cols 44..63 zero-padded), stride 100 == 4 mod 32
        for (int idx = threadIdx.x; idx < 64 * 24; idx += 256) {
            int jj = idx / 24, kc = idx % 24;
            float4 v = make_float4(0.f, 0.f, 0.f, 0.f);
            if (jj < 44)
                v = *(const float4*)&xpl[(size_t)jj * DI + kt + kc * 4];
            *(float4*)&ws[jj * 100 + kc * 4] = v;
        }
        __syncthreads();
        const float* wr0 = ws + lane * 100;
        const float* xr0 = xs + (wv * 2 + 0) * 100;
        const float* xr1 = xs + (wv * 2 + 1) * 100;
        #pragma unroll 4
        for (int kk = 0; kk < 96; kk += 4) {
            float4 xv0 = *(const float4*)&xr0[kk];
            float4 xv1 = *(const float4*)&xr1[kk];
            float4 wv4 = *(const float4*)&wr0[kk];
            acc[0] += xv0.x * wv4.x + xv0.y * wv4.y + xv0.z * wv4.z + xv0.w * wv4.w;
            acc[1] += xv1.x * wv4.x + xv1.y * wv4.y + xv1.z * wv4.z + xv1.w * wv4.w;
        }
        __syncthreads();   // also protects the phase-2 LDS overwrite below
    }
    // phase transition: dbl out (cols 0..43), sdbl + dt_w into LDS
    if (lane < 44) {
        #pragma unroll
        for (int t = 0; t < 2; t++) {
            sdbl[(wv * 2 + t) * 48 + lane] = acc[t];
            dbl[(size_t)(t0 + wv * 2 + t) * 44 + lane] = acc[t];
        }
    }
    const float* dwl = dtw + (size_t)layer * DI * DTR;
    for (int idx = threadIdx.x; idx < DI * DTR; idx += 256) {
        int d = idx / 12, rr = idx % 12;
        sdtw[d * 13 + rr] = dwl[idx];
    }
    __syncthreads();
    // phase 2: dt = softplus(dbl[:, :12] @ dt_w.T + dt_b)
    const float* dbb = dtbias + (size_t)layer * DI;
    for (int idx = threadIdx.x; idx < 8 * DI; idx += 256) {
        int tt = idx / DI, d = idx % DI;
        float a = dbb[d];
        const float* br = sdbl + tt * 48;
        const float* wr = sdtw + d * 13;
        #pragma unroll
        for (int rr = 0; rr < 12; rr++) a += br[rr] * wr[rr];
        dtbuf[(size_t)(t0 + tt) * DI + d] = softplusf(a);
    }
}

// ---------- fused chunked scan: phase A + LDS prefix + replay ----------
// Block: 320 thr = 80 quads; covers all NC=10 chunks of 8 d-channels for one
// batch. grid = BB * DI/8 = 768 = exactly 3 blocks/CU. LDS 10 KB.
__global__ __launch_bounds__(320) void scan_fused(const float* __restrict__ dt,
                                                  const float* xc,
                                                  const float* __restrict__ dbl,
                                                  const float* __restrict__ xz,
                                                  const float* __restrict__ A_log,
                                                  const float* __restrict__ Dskip,
                                                  float* y,
                                                  size_t aoff, size_t doff) {
    __shared__ float sP[NC * 8 * 16];
    __shared__ float sH[NC * 8 * 16];
    int b = blockIdx.x / (DI / 8);
    int dbase = (blockIdx.x % (DI / 8)) * 8;
    int quad = threadIdx.x >> 2;
    int n0 = threadIdx.x & 3;
    int c = quad >> 3;
    int dl = quad & 7;
    int d = dbase + dl;
    float4 Al = *(const float4*)&A_log[aoff + (size_t)d * DS + n0 * 4];
    float A0 = -expf(Al.x), A1 = -expf(Al.y), A2 = -expf(Al.z), A3 = -expf(Al.w);
    int tbase = b * LL + c * LC;

    float h0 = 0.f, h1 = 0.f, h2 = 0.f, h3 = 0.f;
    float P0 = 1.f, P1 = 1.f, P2 = 1.f, P3 = 1.f;
    for (int l = 0; l < LC; l++) {
        size_t t = (size_t)tbase + l;
        float dtv = dt[t * DI + d];
        float xcv = xc[t * DI + d];
        float4 B4 = *(const float4*)&dbl[t * 44 + DTR + n0 * 4];
        float s = dtv * xcv;
        float e0 = __expf(dtv * A0), e1 = __expf(dtv * A1);
        float e2 = __expf(dtv * A2), e3 = __expf(dtv * A3);
        h0 = e0 * h0 + s * B4.x;  P0 *= e0;
        h1 = e1 * h1 + s * B4.y;  P1 *= e1;
        h2 = e2 * h2 + s * B4.z;  P2 *= e2;
        h3 = e3 * h3 + s * B4.w;  P3 *= e3;
    }
    int si = quad * 16 + n0 * 4;
    *(float4*)&sP[si] = make_float4(P0, P1, P2, P3);
    *(float4*)&sH[si] = make_float4(h0, h1, h2, h3);
    __syncthreads();

    h0 = h1 = h2 = h3 = 0.f;
    for (int cc = 0; cc < c; cc++) {
        int gi = (cc * 8 + dl) * 16 + n0 * 4;
        float4 P4 = *(const float4*)&sP[gi];
        float4 H4 = *(const float4*)&sH[gi];
        h0 = P4.x * h0 + H4.x;
        h1 = P4.y * h1 + H4.y;
        h2 = P4.z * h2 + H4.z;
        h3 = P4.w * h3 + H4.w;
    }

    float Dv = Dskip[doff + d];
    for (int l = 0; l < LC; l++) {
        size_t t = (size_t)tbase + l;
        float dtv = dt[t * DI + d];
        float xcv = xc[t * DI + d];
        float4 B4 = *(const float4*)&dbl[t * 44 + DTR + n0 * 4];
        float4 C4 = *(const float4*)&dbl[t * 44 + DTR + DS + n0 * 4];
        float s = dtv * xcv;
        float e0 = __expf(dtv * A0), e1 = __expf(dtv * A1);
        float e2 = __expf(dtv * A2), e3 = __expf(dtv * A3);
        h0 = e0 * h0 + s * B4.x;
        h1 = e1 * h1 + s * B4.y;
        h2 = e2 * h2 + s * B4.z;
        h3 = e3 * h3 + s * B4.w;
        float p = h0 * C4.x + h1 * C4.y + h2 * C4.z + h3 * C4.w;
        p += __shfl_xor(p, 1);
        p += __shfl_xor(p, 2);
        if (n0 == 0) {
            float zg = xz[t * (2 * DI) + DI + d];
            y[t * DI + d] = (p + xcv * Dv) * siluf(zg);
        }
    }
}

// ---------- final: LN(residual + hidden) -> float32, 4 tokens/block ----------
__global__ __launch_bounds__(256) void final_kernel(const float* __restrict__ hidden,
                                                    const float* __restrict__ residual,
                                                    const float* __restrict__ w,
                                                    const float* __restrict__ bias,
                                                    float* __restrict__ out) {
    int t = blockIdx.x * 4 + (threadIdx.x >> 6);
    int lane = threadIdx.x & 63;
    size_t base = (size_t)t * DM;
    float a = residual[base + lane]       + hidden[base + lane];
    float b = residual[base + 64 + lane]  + hidden[base + 64 + lane];
    float c = residual[base + 128 + lane] + hidden[base + 128 + lane];
    float mu = wave_sum64(a + b + c) * (1.f / 192.f);
    float va = a - mu, vb = b - mu, vc = c - mu;
    float var = wave_sum64(va * va + vb * vb + vc * vc) * (1.f / 192.f);
    float inv = rsqrtf(var + EPSV);
    out[base + lane]       = va * inv * w[lane]       + bias[lane];
    out[base + 64 + lane]  = vb * inv * w[64 + lane]  + bias[64 + lane];
    out[base + 128 + lane] = vc * inv * w[128 + lane] + bias[128 + lane];
}

extern "C" void kernel_launch(void* const* d_in, const int* in_sizes, int n_in,
                              void* d_out, int out_size, void* d_ws, size_t ws_size,
                              hipStream_t stream) {
    const float* x_img   = (const float*)d_in[0];
    const float* z_img   = (const float*)d_in[1];
    const float* patch_w = (const float*)d_in[2];
    const float* patch_b = (const float*)d_in[3];
    const float* pos_x   = (const float*)d_in[4];
    const float* pos_z   = (const float*)d_in[5];
    const float* ln_w    = (const float*)d_in[6];
    const float* ln_b    = (const float*)d_in[7];
    const float* in_w    = (const float*)d_in[8];
    const float* conv_w  = (const float*)d_in[9];
    const float* conv_b  = (const float*)d_in[10];
    const float* xproj_w = (const float*)d_in[11];
    const float* dt_w    = (const float*)d_in[12];
    const float* dt_b    = (const float*)d_in[13];
    const float* A_log   = (const float*)d_in[14];
    const float* D_skip  = (const float*)d_in[15];
    const float* out_w   = (const float*)d_in[16];
    const float* fnorm_w = (const float*)d_in[17];
    const float* fnorm_b = (const float*)d_in[18];

    // ws layout (floats), ~45 MB total (<52 MB proven):
    float* hidden   = (float*)d_ws;                         // NT*DM
    float* residual = hidden   + (size_t)NT * DM;           // NT*DM
    float* xz       = residual + (size_t)NT * DM;           // NT*768
    float* xc       = xz       + (size_t)NT * 2 * DI;       // NT*DI
    float* dbl      = xc       + (size_t)NT * DI;           // NT*44
    float* dtbuf    = dbl      + (size_t)NT * 44;           // NT*DI
    float* hn       = hidden;   // alias (read-before-write per thread)
    float* yb       = xc;       // alias (read-before-write per step)

    // z-first concat: z tokens 0..63, x tokens 64..319 (one combined launch)
    {
        dim3 gp((BB * NX + BB * NZ) / 32, 3);   // (160, 3)
        patch_rt<<<gp, 256, 0, stream>>>(x_img, z_img, patch_w, patch_b,
                                         pos_x, pos_z, hidden);
    }

    const int scan_blocks = BB * (DI / 8);   // 768 blocks of 320 thr = 3/CU
    for (int i = 0; i < DEPTH; i++) {
        addnorm_kernel<<<NT / 4, 256, 0, stream>>>(
            hidden, residual, hn, ln_w, ln_b, (size_t)i * DM, i == 0 ? 1 : 0);
        {
            dim3 g(NT / 32, 3);   // 480 blocks, NCOL=256, KT=24 -> 31.5 KB LDS
            gemm_rt<192, 24, 4><<<g, 256, 0, stream>>>(
                hn, in_w, (size_t)i * 768 * 192, xz, 768);
        }
        xpd_kernel<<<NT / 8, 256, 0, stream>>>(
            xz, conv_w, conv_b, xproj_w, dt_w, dt_b, xc, dbl, dtbuf, i);
        scan_fused<<<scan_blocks, 320, 0, stream>>>(
            dtbuf, xc, dbl, xz, A_log, D_skip, yb,
            (size_t)i * DI * DS, (size_t)i * DI);
        {
            dim3 g(NT / 32, 3);   // 480 blocks, NCOL=64, KT=96
            gemm_rt<384, 96, 1><<<g, 256, 0, stream>>>(
                yb, out_w, (size_t)i * 192 * 384, hidden, 192);
        }
    }

    final_kernel<<<NT / 4, 256, 0, stream>>>(hidden, residual, fnorm_w, fnorm_b,
                                             (float*)d_out);
}